// Round 4
// baseline (46.009 us; speedup 1.0000x reference)
//
#include <hip/hip_runtime.h>

// WOMD post-processing v4: v2 structure (one wave = two agents), with the
// cross-lane DS-op chain halved: value-only butterfly argmax + ballot/ffs
// (first-index tie-break), symmetric within-mask lookup (no __shfl(m,idx)),
// scratch-free serial tail on lanes {0,32}, gathers issued before the tail.

#define NSC 64
#define NAG 64
#define NJF 32
#define NSTEP 80
#define KP 6
#define TOUT 16

struct F3 { float x, y, z; };

__global__ __launch_bounds__(64)
void womd_pp4(const float* __restrict__ ag_type,
              const float* __restrict__ trajs,
              const float* __restrict__ scores,
              float* __restrict__ out)
{
    const int tid  = threadIdx.x;
    const int half = tid >> 5;          // agent of the pair
    const int hl   = tid & 31;          // mode index within 32-group
    const int s    = blockIdx.x >> 5;   // scene
    const int p    = blockIdx.x & 31;   // agent-pair
    const int a    = p * 2 + half;      // agent

    __shared__ float exs[2][NJF][2];    // endpoints
    __shared__ float sms[2][NJF];       // softmax scores

    // ---- loads ----
    float raw = scores[((size_t)s * NJF + hl) * NAG + a];
    size_t eoff = (((size_t)(s * NJF + hl) * NAG + a) * NSTEP + (NSTEP - 1)) * 3;
    float exx = trajs[eoff];
    float exy = trajs[eoff + 1];
    const float* at = ag_type + (size_t)(s * NAG + a) * 3;
    const float thresh = at[0] * 2.5f + at[1] * 1.0f + at[2] * 2.0f;

    exs[half][hl][0] = exx;
    exs[half][hl][1] = exy;

    // ---- softmax over 32 modes (same butterfly order as v2: bit-exact) ----
    float mx = raw;
    #pragma unroll
    for (int off = 16; off > 0; off >>= 1)
        mx = fmaxf(mx, __shfl_xor(mx, off, 32));
    float ev = expf(raw - mx);
    float sum = ev;
    #pragma unroll
    for (int off = 16; off > 0; off >>= 1)
        sum += __shfl_xor(sum, off, 32);
    float sm = ev / sum;
    sms[half][hl] = sm;

    __syncthreads();

    // ---- within bitmask row (strict <, sqrt) ----
    unsigned m = 0;
    #pragma unroll
    for (int j = 0; j < NJF; ++j) {
        float dx = exx - exs[half][j][0];
        float dy = exy - exs[half][j][1];
        m |= (sqrtf(dx * dx + dy * dy) < thresh) ? (1u << j) : 0u;
    }

    // ---- MTR NMS: 6 picks. Value-only max butterfly (5 dep DS), then
    // ballot+ffs gives the FIRST lane holding the max (jnp.argmax tie-break).
    // within is symmetric: bit hl of row idx == bit idx of row hl -> no shfl.
    int sel[KP];                         // literal-indexed only (SROA-safe)
    float ls = sm;
    #pragma unroll
    for (int k = 0; k < KP; ++k) {
        float v = ls;
        #pragma unroll
        for (int off = 16; off > 0; off >>= 1)
            v = fmaxf(v, __shfl_xor(v, off, 32));
        unsigned long long bal = __ballot(ls == v);
        unsigned bits = (unsigned)(half ? (bal >> 32) : bal);
        int idx = __ffs(bits) - 1;       // group-local argmax, first index
        sel[k] = idx;
        ls *= ((m >> idx) & 1u) ? 0.01f : 1.0f;   // within pick -> x0.01 else x1.0
        ls = (hl == idx) ? -1.0f : ls;
    }

    // ---- trajectory gather: issue loads NOW (overlap the MPA tail) ----
    F3 pt[3];
    #pragma unroll
    for (int i = 0; i < 3; ++i) {
        int mode = (hl < 16) ? sel[2 * i] : sel[2 * i + 1];   // static sel idx
        int t = hl & 15;
        size_t src = (((size_t)(s * NJF + mode) * NAG + a) * NSTEP + (4 + 5 * t)) * 3;
        pt[i] = *(const F3*)(trajs + src);
    }

    // ---- MPA tail: serial on lanes {0,32}, all state SROA-register ----
    if (hl == 0) {
        float sk[KP], sk0[KP], sx[KP], sy[KP];
        float ssum = 0.f;
        #pragma unroll
        for (int k = 0; k < KP; ++k) {
            int j = sel[k];
            sk[k] = sms[half][j];
            sx[k] = exs[half][j][0];
            sy[k] = exs[half][j][1];
            ssum += sk[k];
        }
        #pragma unroll
        for (int k = 0; k < KP; ++k) { sk[k] /= ssum; sk0[k] = sk[k]; }

        // 6x6 within rows as bitmasks
        unsigned w2[KP];
        #pragma unroll
        for (int i = 0; i < KP; ++i) {
            unsigned r = 0;
            #pragma unroll
            for (int j = 0; j < KP; ++j) {
                float dx = sx[i] - sx[j], dy = sy[i] - sy[j];
                r |= (sqrtf(dx * dx + dy * dy) < thresh) ? (1u << j) : 0u;
            }
            w2[i] = r;
        }

        // stable descending rank from ORIGINAL normalized scores
        int rank[KP];
        #pragma unroll
        for (int j = 0; j < KP; ++j) {
            int r = 0;
            #pragma unroll
            for (int i = 0; i < KP; ++i)
                r += ((sk0[i] > sk0[j]) || (sk0[i] == sk0[j] && i < j)) ? 1 : 0;
            rank[j] = r;
        }

        // sequential MPA scan in rank order (select chains, literal idx only)
        #pragma unroll
        for (int t = 0; t < KP; ++t) {
            float sk_k = sk[0]; unsigned w2k = w2[0];
            #pragma unroll
            for (int j = 1; j < KP; ++j) {
                bool is = (rank[j] == t);
                sk_k = is ? sk[j] : sk_k;
                w2k  = is ? w2[j] : w2k;
            }
            bool any = false;
            #pragma unroll
            for (int j = 0; j < KP; ++j)
                any = any || ((((w2k >> j) & 1u) != 0u) && (sk[j] > sk_k));
            #pragma unroll
            for (int j = 0; j < KP; ++j)
                if (rank[j] == t && any) sk[j] = 0.001f;
        }

        // normalize; softmax(log p / 0.5) == p^2 / sum(p^2)  (same FP order as v2)
        float s2 = 0.f;
        #pragma unroll
        for (int k = 0; k < KP; ++k) s2 += sk[k];
        #pragma unroll
        for (int k = 0; k < KP; ++k) sk[k] /= s2;
        float q[KP]; float s3 = 0.f;
        #pragma unroll
        for (int k = 0; k < KP; ++k) { q[k] = sk[k] * sk[k]; s3 += q[k]; }

        const size_t SCBASE = (size_t)NSC * NAG * KP * TOUT * 3;
        size_t scb = SCBASE + ((size_t)s * NAG + a) * KP;
        #pragma unroll
        for (int k = 0; k < KP; ++k) out[scb + k] = q[k] / s3;
    }

    // ---- trajectory stores (loads were in flight during the tail) ----
    size_t ob = ((size_t)s * NAG + a) * (KP * TOUT * 3);
    #pragma unroll
    for (int i = 0; i < 3; ++i) {
        *(F3*)(out + ob + (size_t)(hl + 32 * i) * 3) = pt[i];
    }
}

extern "C" void kernel_launch(void* const* d_in, const int* in_sizes, int n_in,
                              void* d_out, int out_size, void* d_ws, size_t ws_size,
                              hipStream_t stream) {
    const float* ag_type = (const float*)d_in[0];
    const float* trajs   = (const float*)d_in[1];
    const float* scores  = (const float*)d_in[2];
    float* out = (float*)d_out;

    womd_pp4<<<NSC * (NAG / 2), 64, 0, stream>>>(ag_type, trajs, scores, out);
}

// Round 5
// 41.648 us; speedup vs baseline: 1.1047x; 1.1047x over previous
//
#include <hip/hip_runtime.h>

// WOMD post-processing v5: two-kernel split.
//  A) womd_sel  — v2's selection code verbatim (measured best, bit-exact):
//     softmax, within-mask, MTR-NMS, MPA tail, score output. Additionally
//     writes per-(agent,mode) trajectory base offsets to d_ws.
//  B) womd_gather — pure strided gather-copy of the selected trajectories,
//     one F3 per thread, 393216 threads = 24 waves/CU (high TLP to hide
//     scattered-load latency that kernel A's 2 waves/SIMD could not).

#define NSC 64
#define NAG 64
#define NJF 32
#define NSTEP 80
#define KP 6
#define TOUT 16

struct F3 { float x, y, z; };

__global__ __launch_bounds__(64)
void womd_sel(const float* __restrict__ ag_type,
              const float* __restrict__ trajs,
              const float* __restrict__ scores,
              float* __restrict__ out,
              int* __restrict__ selbase)
{
    const int tid  = threadIdx.x;
    const int half = tid >> 5;          // which agent of the pair
    const int hl   = tid & 31;          // lane within 32-group = mode index
    const int s    = blockIdx.x >> 5;   // scene
    const int p    = blockIdx.x & 31;   // agent-pair
    const int a    = p * 2 + half;      // agent

    __shared__ float exs[2][NJF][2];    // endpoints per half
    __shared__ float sms[2][NJF];       // softmax scores per half

    // ---- loads ----
    float raw = scores[((size_t)s * NJF + hl) * NAG + a];
    size_t eoff = (((size_t)(s * NJF + hl) * NAG + a) * NSTEP + (NSTEP - 1)) * 3;
    float exx = trajs[eoff];
    float exy = trajs[eoff + 1];
    const float* at = ag_type + (size_t)(s * NAG + a) * 3;
    const float thresh = at[0] * 2.5f + at[1] * 1.0f + at[2] * 2.0f;

    exs[half][hl][0] = exx;
    exs[half][hl][1] = exy;

    // ---- softmax over 32 modes (butterfly, 1 expf/lane) ----
    float mx = raw;
    #pragma unroll
    for (int off = 16; off > 0; off >>= 1)
        mx = fmaxf(mx, __shfl_xor(mx, off, 32));
    float ev = expf(raw - mx);
    float sum = ev;
    #pragma unroll
    for (int off = 16; off > 0; off >>= 1)
        sum += __shfl_xor(sum, off, 32);
    float sm = ev / sum;
    sms[half][hl] = sm;

    __syncthreads();

    // ---- within bitmask row (strict <, sqrt) ----
    unsigned m = 0;
    #pragma unroll 8
    for (int j = 0; j < NJF; ++j) {
        float dx = exx - exs[half][j][0];
        float dy = exy - exs[half][j][1];
        if (sqrtf(dx * dx + dy * dy) < thresh) m |= (1u << j);
    }

    // ---- MTR NMS: 6 picks (v2's value+index butterfly, first-index ties) ----
    int sel[KP];
    float ls = sm;
    #pragma unroll
    for (int k = 0; k < KP; ++k) {
        float v = ls; int idx = hl;
        #pragma unroll
        for (int off = 16; off > 0; off >>= 1) {
            float ov = __shfl_xor(v, off, 32);
            int   oi = __shfl_xor(idx, off, 32);
            if (ov > v || (ov == v && oi < idx)) { v = ov; idx = oi; }
        }
        unsigned wb = __shfl(m, idx, 32);          // within-row of the pick
        ls *= ((wb >> hl) & 1u) ? 0.01f : 1.0f;
        if (hl == idx) ls = -1.0f;
        sel[k] = idx;
    }

    // ---- MPA tail: serial on lanes {0,32} (v2 verbatim) ----
    if (hl == 0) {
        float sk[KP], sx[KP], sy[KP];
        float ssum = 0.f;
        #pragma unroll
        for (int k = 0; k < KP; ++k) {
            sk[k]  = sms[half][sel[k]];
            ssum  += sk[k];
            sx[k]  = exs[half][sel[k]][0];
            sy[k]  = exs[half][sel[k]][1];
        }
        #pragma unroll
        for (int k = 0; k < KP; ++k) sk[k] /= ssum;

        bool w2[KP][KP];
        #pragma unroll
        for (int i = 0; i < KP; ++i)
            #pragma unroll
            for (int j = 0; j < KP; ++j) {
                float dx = sx[i] - sx[j], dy = sy[i] - sy[j];
                w2[i][j] = sqrtf(dx * dx + dy * dy) < thresh;
            }

        int order[KP]; bool used[KP] = {false,false,false,false,false,false};
        #pragma unroll
        for (int t = 0; t < KP; ++t) {
            int best = -1; float bv = 0.f;
            #pragma unroll
            for (int j = 0; j < KP; ++j)
                if (!used[j] && (best < 0 || sk[j] > bv)) { best = j; bv = sk[j]; }
            order[t] = best; used[best] = true;
        }
        #pragma unroll
        for (int t = 0; t < KP; ++t) {
            int k = order[t];
            bool any = false;
            #pragma unroll
            for (int j = 0; j < KP; ++j)
                if (w2[k][j] && sk[j] > sk[k]) any = true;
            if (any) sk[k] = 0.001f;
        }

        float s2 = 0.f;
        #pragma unroll
        for (int k = 0; k < KP; ++k) s2 += sk[k];
        #pragma unroll
        for (int k = 0; k < KP; ++k) sk[k] /= s2;
        float s3 = 0.f; float q[KP];
        #pragma unroll
        for (int k = 0; k < KP; ++k) { q[k] = sk[k] * sk[k]; s3 += q[k]; }

        const size_t SCBASE = (size_t)NSC * NAG * KP * TOUT * 3;
        size_t scb = SCBASE + ((size_t)s * NAG + a) * KP;
        #pragma unroll
        for (int k = 0; k < KP; ++k) out[scb + k] = q[k] / s3;

        // per-(agent,mode) trajectory base element-offsets for the gather
        int bm = (s * NAG + a) * KP;
        #pragma unroll
        for (int k = 0; k < KP; ++k)
            selbase[bm + k] = ((s * NJF + sel[k]) * NAG + a) * (NSTEP * 3);
    }
}

// ---- Kernel B: gather-copy. One F3 per thread; 393216 threads. ----
__global__ __launch_bounds__(256)
void womd_gather(const float* __restrict__ trajs,
                 const int* __restrict__ selbase,
                 float* __restrict__ out)
{
    int e  = blockIdx.x * 256 + threadIdx.x;   // 0 .. 393215 = (b*6+m)*16 + t
    int t  = e & 15;
    int bm = e >> 4;
    int base = selbase[bm];
    F3 v = *(const F3*)(trajs + (size_t)base + (size_t)(4 + 5 * t) * 3);
    *(F3*)(out + (size_t)e * 3) = v;
}

extern "C" void kernel_launch(void* const* d_in, const int* in_sizes, int n_in,
                              void* d_out, int out_size, void* d_ws, size_t ws_size,
                              hipStream_t stream) {
    const float* ag_type = (const float*)d_in[0];
    const float* trajs   = (const float*)d_in[1];
    const float* scores  = (const float*)d_in[2];
    float* out = (float*)d_out;
    int* selbase = (int*)d_ws;                  // 4096*6 ints = 96 KB

    womd_sel<<<NSC * (NAG / 2), 64, 0, stream>>>(ag_type, trajs, scores, out, selbase);

    const int total = NSC * NAG * KP * TOUT;    // 393216 F3 elements
    womd_gather<<<total / 256, 256, 0, stream>>>(trajs, selbase, out);
}

// Round 6
// 32.726 us; speedup vs baseline: 1.4059x; 1.2726x over previous
//
#include <hip/hip_runtime.h>

// WOMD post-processing v6 == v2 VERBATIM (reproducibility A/B).
// v2 measured 33.2 us; v3/v4/v5 "improvements" measured 40.8/46.0/41.6.
// Resubmitting the best-known kernel unchanged to establish the noise band.

#define NSC 64
#define NAG 64
#define NJF 32
#define NSTEP 80
#define KP 6
#define TOUT 16

struct F3 { float x, y, z; };

__global__ __launch_bounds__(64)
void womd_pp2(const float* __restrict__ ag_type,
              const float* __restrict__ trajs,
              const float* __restrict__ scores,
              float* __restrict__ out)
{
    const int tid  = threadIdx.x;
    const int half = tid >> 5;          // which agent of the pair
    const int hl   = tid & 31;          // lane within 32-group = mode index
    const int s    = blockIdx.x >> 5;   // scene
    const int p    = blockIdx.x & 31;   // agent-pair
    const int a    = p * 2 + half;      // agent

    __shared__ float exs[2][NJF][2];    // endpoints per half
    __shared__ float sms[2][NJF];       // softmax scores per half
    __shared__ int   selsh[2][KP];      // MTR picks per half

    // ---- loads (issued up front) ----
    float raw = scores[((size_t)s * NJF + hl) * NAG + a];
    size_t eoff = (((size_t)(s * NJF + hl) * NAG + a) * NSTEP + (NSTEP - 1)) * 3;
    float exx = trajs[eoff];
    float exy = trajs[eoff + 1];
    const float* at = ag_type + (size_t)(s * NAG + a) * 3;
    const float thresh = at[0] * 2.5f + at[1] * 1.0f + at[2] * 2.0f;

    exs[half][hl][0] = exx;
    exs[half][hl][1] = exy;

    // ---- softmax over 32 modes (width-32 butterfly, 1 expf/lane) ----
    float mx = raw;
    #pragma unroll
    for (int off = 16; off > 0; off >>= 1)
        mx = fmaxf(mx, __shfl_xor(mx, off, 32));
    float ev = expf(raw - mx);
    float sum = ev;
    #pragma unroll
    for (int off = 16; off > 0; off >>= 1)
        sum += __shfl_xor(sum, off, 32);
    float sm = ev / sum;
    sms[half][hl] = sm;

    __syncthreads();

    // ---- within bitmask: row hl (strict <, sqrt like jnp.linalg.norm) ----
    unsigned m = 0;
    #pragma unroll 8
    for (int j = 0; j < NJF; ++j) {
        float dx = exx - exs[half][j][0];
        float dy = exy - exs[half][j][1];
        if (sqrtf(dx * dx + dy * dy) < thresh) m |= (1u << j);
    }

    // ---- MTR NMS: 6 picks, wave-parallel ----
    float ls = sm;
    #pragma unroll
    for (int k = 0; k < KP; ++k) {
        // argmax with first-index tie-break (matches jnp.argmax)
        float v = ls; int idx = hl;
        #pragma unroll
        for (int off = 16; off > 0; off >>= 1) {
            float ov = __shfl_xor(v, off, 32);
            int   oi = __shfl_xor(idx, off, 32);
            if (ov > v || (ov == v && oi < idx)) { v = ov; idx = oi; }
        }
        unsigned wb = __shfl(m, idx, 32);          // within-row of the pick
        // sc *= within ? 0.01 : (0.99f+0.01f == 1.0f)
        ls *= ((wb >> hl) & 1u) ? 0.01f : 1.0f;
        if (hl == idx) ls = -1.0f;
        if (hl == 0) selsh[half][k] = idx;
    }
    __syncthreads();

    // ---- trajectory gather: issue loads NOW (overlap with MPA tail) ----
    // 96 points (6 modes x 16 steps) per agent, 3 per lane, 12B each.
    F3 pt[3];
    #pragma unroll
    for (int i = 0; i < 3; ++i) {
        int e  = hl + 32 * i;          // 0..95
        int mm = e >> 4;               // mode 0..5
        int t  = e & 15;               // step 0..15
        int sj = selsh[half][mm];
        size_t src = (((size_t)(s * NJF + sj) * NAG + a) * NSTEP + (4 + 5 * t)) * 3;
        pt[i] = *(const F3*)(trajs + src);
    }

    // ---- MPA tail: serial 6x6, lanes 0 and 32 concurrently ----
    if (hl == 0) {
        int   sel[KP];
        float sk[KP], sx[KP], sy[KP];
        float ssum = 0.f;
        #pragma unroll
        for (int k = 0; k < KP; ++k) {
            sel[k] = selsh[half][k];
            sk[k]  = sms[half][sel[k]];
            ssum  += sk[k];
            sx[k]  = exs[half][sel[k]][0];
            sy[k]  = exs[half][sel[k]][1];
        }
        #pragma unroll
        for (int k = 0; k < KP; ++k) sk[k] /= ssum;

        bool w2[KP][KP];
        #pragma unroll
        for (int i = 0; i < KP; ++i)
            #pragma unroll
            for (int j = 0; j < KP; ++j) {
                float dx = sx[i] - sx[j], dy = sy[i] - sy[j];
                w2[i][j] = sqrtf(dx * dx + dy * dy) < thresh;
            }

        // stable descending argsort (ties -> lower index), then MPA scan
        int order[KP]; bool used[KP] = {false,false,false,false,false,false};
        #pragma unroll
        for (int t = 0; t < KP; ++t) {
            int best = -1; float bv = 0.f;
            #pragma unroll
            for (int j = 0; j < KP; ++j)
                if (!used[j] && (best < 0 || sk[j] > bv)) { best = j; bv = sk[j]; }
            order[t] = best; used[best] = true;
        }
        #pragma unroll
        for (int t = 0; t < KP; ++t) {
            int k = order[t];
            bool any = false;
            #pragma unroll
            for (int j = 0; j < KP; ++j)
                if (w2[k][j] && sk[j] > sk[k]) any = true;
            if (any) sk[k] = 0.001f;
        }

        // normalize; softmax(log p / 0.5) == p^2 / sum(p^2)
        float s2 = 0.f;
        #pragma unroll
        for (int k = 0; k < KP; ++k) s2 += sk[k];
        #pragma unroll
        for (int k = 0; k < KP; ++k) sk[k] /= s2;
        float s3 = 0.f; float q[KP];
        #pragma unroll
        for (int k = 0; k < KP; ++k) { q[k] = sk[k] * sk[k]; s3 += q[k]; }

        const size_t SCBASE = (size_t)NSC * NAG * KP * TOUT * 3;
        size_t scb = SCBASE + ((size_t)s * NAG + a) * KP;
        #pragma unroll
        for (int k = 0; k < KP; ++k) out[scb + k] = q[k] / s3;
    }

    // ---- trajectory stores (loads were in flight during the tail) ----
    size_t ob = ((size_t)s * NAG + a) * (KP * TOUT * 3);
    #pragma unroll
    for (int i = 0; i < 3; ++i) {
        int e = hl + 32 * i;
        *(F3*)(out + ob + (size_t)e * 3) = pt[i];
    }
}

extern "C" void kernel_launch(void* const* d_in, const int* in_sizes, int n_in,
                              void* d_out, int out_size, void* d_ws, size_t ws_size,
                              hipStream_t stream) {
    const float* ag_type = (const float*)d_in[0];
    const float* trajs   = (const float*)d_in[1];
    const float* scores  = (const float*)d_in[2];
    float* out = (float*)d_out;

    womd_pp2<<<NSC * (NAG / 2), 64, 0, stream>>>(ag_type, trajs, scores, out);
}